// Round 2
// baseline (274.950 us; speedup 1.0000x reference)
//
#include <hip/hip_runtime.h>

// y[b,o,p] = sum_c wproj[o,c] * illu[b,c,p] * (sum_i wmix[c,i]*x[b,i,p])
// (attention collapses: DIM==HEADS==64 => softmax over singleton == 1.0;
//  0.6/0.4 output mix commutes onto the weights: wmix = .6*wvs + .4*wvt)
//
// R8 == R7 resubmit (R7 bench died in the container broker before running;
// no counters, no verdict). Persistent-tile restructure vs R6:
//  - grid = 1024 blocks (exactly 4/CU resident), TPB=4 tiles each; weights
//    loaded + converted ONCE per block (amortized 4x, -147MB L2 traffic).
//  - x B-fragments load global->VGPR directly per lane (8 k-consecutive
//    channels at one pixel = 16 scalar loads, 4x64B segments/inst): no xs,
//    no ils, no LDS transpose, ZERO barriers in the tile loop.
//  - T14 prefetch: x(t+1) issued right after x(t) converts, illu(t+1) right
//    after gate(t) consumes illu(t) -> load-use distance = one full tile of
//    MFMA work; barrier-free waves self-stagger so the memory pipe stays fed.
//  - LDS 58.9KB -> 25.5KB, launch_bounds(256,4) -> 4 blocks/CU, 16 waves/CU.
// u' handoff between phases stays the XH row-bounce: wave wv exclusively owns
// rows nb..nb+15 for the whole kernel; same-wave DS ops are ordered (pattern
// verified in R4-R6, absmax 1.95e-3).

#define HW 65536
#define CH 64
#define PT 64    // pixels per tile
#define SX 68    // bf16 row stride: 136B rows, 8B-aligned, bank-spread frags
#define TPB 4    // tiles per block -> grid 1024 = 4 blocks/CU fully resident

typedef short s4_t __attribute__((ext_vector_type(4)));
typedef short s8_t __attribute__((ext_vector_type(8)));
typedef float f4_t __attribute__((ext_vector_type(4)));

static __device__ __forceinline__ unsigned short f2bf(float f) {
  unsigned u = __float_as_uint(f);
  return (unsigned short)((u + 0x7fffu + ((u >> 16) & 1u)) >> 16);  // RNE
}
static __device__ __forceinline__ s8_t ld8(const unsigned short* p) {
  s4_t lo = *(const s4_t*)p;        // rows 8B-aligned: 2x ds_read_b64
  s4_t hi = *(const s4_t*)(p + 4);
  s8_t r = {lo[0], lo[1], lo[2], lo[3], hi[0], hi[1], hi[2], hi[3]};
  return r;
}

__global__ __launch_bounds__(256, 4) void fused_hsattn(
    const float* __restrict__ x, const float* __restrict__ illu,
    const float* __restrict__ wvs, const float* __restrict__ wvt,
    const float* __restrict__ wproj, float* __restrict__ out) {
  __shared__ __align__(16) unsigned short WM[CH * SX];   // 8.5 KB wmix  [c][i]
  __shared__ __align__(16) unsigned short WP[CH * SX];   // 8.5 KB wproj [o][c]
  __shared__ __align__(16) unsigned short XH[PT * SX];   // 8.5 KB u'^T bounce

  const int tid  = threadIdx.x;
  const int lane = tid & 63;
  const int wv   = tid >> 6;
  const int n15  = lane & 15;
  const int q    = lane >> 4;
  const int nb   = wv * 16;                    // wave owns pixels nb..nb+15

  // 4|1024 => all TPB tiles of a block share one batch image; pixels are
  // contiguous: tile t covers [pix0 + t*64, +64).
  const int tile0 = blockIdx.x * TPB;
  const int bb    = tile0 >> 10;
  const int pix0  = (tile0 & 1023) << 6;
  const int base0 = bb * CH * HW + pix0;       // <=12.7M floats: fits int

  // ---- (1) weight loads FIRST (oldest vmcnt slots; L2-hot after wave 1)
  f4_t wa[4], wb[4], wc[4];
#pragma unroll
  for (int it = 0; it < 4; ++it) {
    int j4 = (it * 256 + tid) * 4;
    wa[it] = *(const f4_t*)(wvs + j4);
    wb[it] = *(const f4_t*)(wvt + j4);
    wc[it] = *(const f4_t*)(wproj + j4);
  }

  // ---- (2) tile-0 prefetch (younger than weights: the weight-convert
  // vmcnt wait leaves these 32 loads in flight).
  // x frag: lane (q,n15) needs x[k = kc*32+q*8+j][pix nb+n15] -> per inst the
  // wave touches 4 rows x 16 consecutive floats = 4x64B segments (coalesced).
  float xv[16], iv[16];
  {
    const float* xb = x + base0 + nb + n15;
    const float* ib = illu + base0 + nb + n15;
#pragma unroll
    for (int kc = 0; kc < 2; ++kc)
#pragma unroll
      for (int j = 0; j < 8; ++j)
        xv[kc * 8 + j] = xb[(kc * 32 + q * 8 + j) * HW];
#pragma unroll
    for (int mt = 0; mt < 4; ++mt)
#pragma unroll
      for (int r = 0; r < 4; ++r)
        iv[mt * 4 + r] = ib[(mt * 16 + q * 4 + r) * HW];
  }

  // ---- (3) convert + stage weights (once per block)
#pragma unroll
  for (int it = 0; it < 4; ++it) {
    int idx = it * 256 + tid;                  // float4 index 0..1023
    int r = idx >> 4, c4 = (idx & 15) * 4;
    s4_t m, w;
#pragma unroll
    for (int j = 0; j < 4; ++j) {
      m[j] = (short)f2bf(0.6f * wa[it][j] + 0.4f * wb[it][j]);
      w[j] = (short)f2bf(wc[it][j]);
    }
    *(s4_t*)(WM + r * SX + c4) = m;
    *(s4_t*)(WP + r * SX + c4) = w;
  }
  __syncthreads();   // the ONLY barrier: publishes WM/WP

  // ---- (4) tile loop: barrier-free, register-double-buffered via unroll
#pragma unroll
  for (int t = 0; t < TPB; ++t) {
    const int base = base0 + t * PT;

    // B fragments for phase 1 (frees xv for the t+1 prefetch)
    s8_t B0, B1;
#pragma unroll
    for (int j = 0; j < 8; ++j) {
      B0[j] = (short)f2bf(xv[j]);
      B1[j] = (short)f2bf(xv[8 + j]);
    }

    // issue x(t+1) now: load-use distance = phase1+gate+phase2 of tile t
    if (t + 1 < TPB) {
      const float* xb = x + base0 + (t + 1) * PT + nb + n15;
#pragma unroll
      for (int kc = 0; kc < 2; ++kc)
#pragma unroll
        for (int j = 0; j < 8; ++j)
          xv[kc * 8 + j] = xb[(kc * 32 + q * 8 + j) * HW];
    }

    // phase 1: u = wmix * x   (A[m=n15][k], B[n=pixel n15][k])
    f4_t acc[4];
#pragma unroll
    for (int i = 0; i < 4; ++i) acc[i] = (f4_t){0.f, 0.f, 0.f, 0.f};
#pragma unroll
    for (int mt = 0; mt < 4; ++mt) {
      s8_t A0 = ld8(WM + (mt * 16 + n15) * SX + q * 8);
      acc[mt] = __builtin_amdgcn_mfma_f32_16x16x32_bf16(A0, B0, acc[mt], 0, 0, 0);
      s8_t A1 = ld8(WM + (mt * 16 + n15) * SX + 32 + q * 8);
      acc[mt] = __builtin_amdgcn_mfma_f32_16x16x32_bf16(A1, B1, acc[mt], 0, 0, 0);
    }

    // gate with illu, write u'^T into this wave's private XH rows.
    // C/D layout: row c = mt*16 + q*4 + r, col = pixel nb+n15.
#pragma unroll
    for (int mt = 0; mt < 4; ++mt) {
      s4_t h;
#pragma unroll
      for (int r = 0; r < 4; ++r)
        h[r] = (short)f2bf(acc[mt][r] * iv[mt * 4 + r]);
      *(s4_t*)(XH + (nb + n15) * SX + mt * 16 + q * 4) = h;
    }

    // issue illu(t+1) now (iv consumed by the gate above)
    if (t + 1 < TPB) {
      const float* ib = illu + base0 + (t + 1) * PT + nb + n15;
#pragma unroll
      for (int mt = 0; mt < 4; ++mt)
#pragma unroll
        for (int r = 0; r < 4; ++r)
          iv[mt * 4 + r] = ib[(mt * 16 + q * 4 + r) * HW];
    }

    // phase 2: y = wproj * u'  (B from own XH rows; same-wave DS ordered)
    f4_t acc2[4];
#pragma unroll
    for (int i = 0; i < 4; ++i) acc2[i] = (f4_t){0.f, 0.f, 0.f, 0.f};
#pragma unroll
    for (int kc = 0; kc < 2; ++kc) {
      s8_t B = ld8(XH + (nb + n15) * SX + kc * 32 + q * 8);
#pragma unroll
      for (int mt = 0; mt < 4; ++mt) {
        s8_t A = ld8(WP + (mt * 16 + n15) * SX + kc * 32 + q * 8);
        acc2[mt] = __builtin_amdgcn_mfma_f32_16x16x32_bf16(A, B, acc2[mt], 0, 0, 0);
      }
    }

    // store (fire-and-forget; 4x64B segments/inst, merges in L2)
#pragma unroll
    for (int mt = 0; mt < 4; ++mt) {
      float* op = out + base + (mt * 16 + q * 4) * HW + nb + n15;
      f4_t a = acc2[mt];
#pragma unroll
      for (int r = 0; r < 4; ++r) op[r * HW] = a[r];
    }
  }
}

extern "C" void kernel_launch(void* const* d_in, const int* in_sizes, int n_in,
                              void* d_out, int out_size, void* d_ws, size_t ws_size,
                              hipStream_t stream) {
  const float* x     = (const float*)d_in[0];   // (4,64,256,256)
  const float* illu  = (const float*)d_in[1];   // (4,64,256,256)
  const float* wvs   = (const float*)d_in[4];   // w_v_spec (64,64)
  const float* wvt   = (const float*)d_in[7];   // w_v_spat (64,64)
  const float* wproj = (const float*)d_in[10];  // w_proj   (64,64)
  float* out = (float*)d_out;

  fused_hsattn<<<4 * (HW / PT) / TPB, 256, 0, stream>>>(x, illu, wvs, wvt,
                                                        wproj, out);
}

// Round 3
// 205.394 us; speedup vs baseline: 1.3386x; 1.3386x over previous
//
#include <hip/hip_runtime.h>

// y[b,o,p] = sum_c wproj[o,c] * illu[b,c,p] * (sum_i wmix[c,i]*x[b,i,p])
// (attention collapses: DIM==HEADS==64 => softmax over singleton == 1.0;
//  0.6/0.4 output mix commutes onto the weights: wmix = .6*wvs + .4*wvt)
//
// R9 = R8 + one raw s_barrier per tile. R8's counters: occupancy fix worked
// (Occ 40%, VGPR 64, VALU 4.4%) but hbm_bytes tripled (WRITE 237MB on a 64MB
// output, FETCH 168MB) -> 143us. Cause: every global access here is a
// 64B-per-wave segment (lanes cover 16 consecutive pixels; a 128B line = 32
// pixels), so line halves belong to waves 0/1 (2/3) of the block. R6's
// barriers kept waves in lockstep -> halves merged in L2 (WRITE was exactly
// 64MB, same store code). R8's barrier-free self-stagger let waves drift
// beyond L2 line lifetime -> partial-line writebacks + RMW re-fetches.
// Fix: __builtin_amdgcn_s_barrier() at tile end — bounds drift to <=1 tile
// (~1-2us << L2 lifetime) with NO vmcnt drain: no cross-wave data sharing in
// the loop (XH rows are wave-private), so the raw barrier is legal and the
// t+1 register prefetch stays in flight across it (keeps the T14 overlap).

#define HW 65536
#define CH 64
#define PT 64    // pixels per tile
#define SX 68    // bf16 row stride: 136B rows, 8B-aligned, bank-spread frags
#define TPB 4    // tiles per block -> grid 1024 = 4 blocks/CU fully resident

typedef short s4_t __attribute__((ext_vector_type(4)));
typedef short s8_t __attribute__((ext_vector_type(8)));
typedef float f4_t __attribute__((ext_vector_type(4)));

static __device__ __forceinline__ unsigned short f2bf(float f) {
  unsigned u = __float_as_uint(f);
  return (unsigned short)((u + 0x7fffu + ((u >> 16) & 1u)) >> 16);  // RNE
}
static __device__ __forceinline__ s8_t ld8(const unsigned short* p) {
  s4_t lo = *(const s4_t*)p;        // rows 8B-aligned: 2x ds_read_b64
  s4_t hi = *(const s4_t*)(p + 4);
  s8_t r = {lo[0], lo[1], lo[2], lo[3], hi[0], hi[1], hi[2], hi[3]};
  return r;
}

__global__ __launch_bounds__(256, 4) void fused_hsattn(
    const float* __restrict__ x, const float* __restrict__ illu,
    const float* __restrict__ wvs, const float* __restrict__ wvt,
    const float* __restrict__ wproj, float* __restrict__ out) {
  __shared__ __align__(16) unsigned short WM[CH * SX];   // 8.5 KB wmix  [c][i]
  __shared__ __align__(16) unsigned short WP[CH * SX];   // 8.5 KB wproj [o][c]
  __shared__ __align__(16) unsigned short XH[PT * SX];   // 8.5 KB u'^T bounce

  const int tid  = threadIdx.x;
  const int lane = tid & 63;
  const int wv   = tid >> 6;
  const int n15  = lane & 15;
  const int q    = lane >> 4;
  const int nb   = wv * 16;                    // wave owns pixels nb..nb+15

  // 4|1024 => all TPB tiles of a block share one batch image; pixels are
  // contiguous: tile t covers [pix0 + t*64, +64).
  const int tile0 = blockIdx.x * TPB;
  const int bb    = tile0 >> 10;
  const int pix0  = (tile0 & 1023) << 6;
  const int base0 = bb * CH * HW + pix0;       // <=12.7M floats: fits int

  // ---- (1) weight loads FIRST (oldest vmcnt slots; L2-hot after wave 1)
  f4_t wa[4], wb[4], wc[4];
#pragma unroll
  for (int it = 0; it < 4; ++it) {
    int j4 = (it * 256 + tid) * 4;
    wa[it] = *(const f4_t*)(wvs + j4);
    wb[it] = *(const f4_t*)(wvt + j4);
    wc[it] = *(const f4_t*)(wproj + j4);
  }

  // ---- (2) tile-0 prefetch (younger than weights: the weight-convert
  // vmcnt wait leaves these 32 loads in flight).
  // x frag: lane (q,n15) needs x[k = kc*32+q*8+j][pix nb+n15] -> per inst the
  // wave touches 4 rows x 16 consecutive floats = 4x64B segments (coalesced).
  float xv[16], iv[16];
  {
    const float* xb = x + base0 + nb + n15;
    const float* ib = illu + base0 + nb + n15;
#pragma unroll
    for (int kc = 0; kc < 2; ++kc)
#pragma unroll
      for (int j = 0; j < 8; ++j)
        xv[kc * 8 + j] = xb[(kc * 32 + q * 8 + j) * HW];
#pragma unroll
    for (int mt = 0; mt < 4; ++mt)
#pragma unroll
      for (int r = 0; r < 4; ++r)
        iv[mt * 4 + r] = ib[(mt * 16 + q * 4 + r) * HW];
  }

  // ---- (3) convert + stage weights (once per block)
#pragma unroll
  for (int it = 0; it < 4; ++it) {
    int idx = it * 256 + tid;                  // float4 index 0..1023
    int r = idx >> 4, c4 = (idx & 15) * 4;
    s4_t m, w;
#pragma unroll
    for (int j = 0; j < 4; ++j) {
      m[j] = (short)f2bf(0.6f * wa[it][j] + 0.4f * wb[it][j]);
      w[j] = (short)f2bf(wc[it][j]);
    }
    *(s4_t*)(WM + r * SX + c4) = m;
    *(s4_t*)(WP + r * SX + c4) = w;
  }
  __syncthreads();   // publishes WM/WP (the only full barrier)

  // ---- (4) tile loop: one raw s_barrier per tile bounds wave drift so
  // complementary 64B line-halves (waves 0/1, 2/3) merge in L2.
#pragma unroll
  for (int t = 0; t < TPB; ++t) {
    const int base = base0 + t * PT;

    // B fragments for phase 1 (frees xv for the t+1 prefetch)
    s8_t B0, B1;
#pragma unroll
    for (int j = 0; j < 8; ++j) {
      B0[j] = (short)f2bf(xv[j]);
      B1[j] = (short)f2bf(xv[8 + j]);
    }

    // issue x(t+1) now: load-use distance = phase1+gate+phase2 of tile t
    if (t + 1 < TPB) {
      const float* xb = x + base0 + (t + 1) * PT + nb + n15;
#pragma unroll
      for (int kc = 0; kc < 2; ++kc)
#pragma unroll
        for (int j = 0; j < 8; ++j)
          xv[kc * 8 + j] = xb[(kc * 32 + q * 8 + j) * HW];
    }

    // phase 1: u = wmix * x   (A[m=n15][k], B[n=pixel n15][k])
    f4_t acc[4];
#pragma unroll
    for (int i = 0; i < 4; ++i) acc[i] = (f4_t){0.f, 0.f, 0.f, 0.f};
#pragma unroll
    for (int mt = 0; mt < 4; ++mt) {
      s8_t A0 = ld8(WM + (mt * 16 + n15) * SX + q * 8);
      acc[mt] = __builtin_amdgcn_mfma_f32_16x16x32_bf16(A0, B0, acc[mt], 0, 0, 0);
      s8_t A1 = ld8(WM + (mt * 16 + n15) * SX + 32 + q * 8);
      acc[mt] = __builtin_amdgcn_mfma_f32_16x16x32_bf16(A1, B1, acc[mt], 0, 0, 0);
    }

    // gate with illu, write u'^T into this wave's private XH rows.
    // C/D layout: row c = mt*16 + q*4 + r, col = pixel nb+n15.
#pragma unroll
    for (int mt = 0; mt < 4; ++mt) {
      s4_t h;
#pragma unroll
      for (int r = 0; r < 4; ++r)
        h[r] = (short)f2bf(acc[mt][r] * iv[mt * 4 + r]);
      *(s4_t*)(XH + (nb + n15) * SX + mt * 16 + q * 4) = h;
    }

    // issue illu(t+1) now (iv consumed by the gate above)
    if (t + 1 < TPB) {
      const float* ib = illu + base0 + (t + 1) * PT + nb + n15;
#pragma unroll
      for (int mt = 0; mt < 4; ++mt)
#pragma unroll
        for (int r = 0; r < 4; ++r)
          iv[mt * 4 + r] = ib[(mt * 16 + q * 4 + r) * HW];
    }

    // phase 2: y = wproj * u'  (B from own XH rows; same-wave DS ordered)
    f4_t acc2[4];
#pragma unroll
    for (int i = 0; i < 4; ++i) acc2[i] = (f4_t){0.f, 0.f, 0.f, 0.f};
#pragma unroll
    for (int kc = 0; kc < 2; ++kc) {
      s8_t B = ld8(XH + (nb + n15) * SX + kc * 32 + q * 8);
#pragma unroll
      for (int mt = 0; mt < 4; ++mt) {
        s8_t A = ld8(WP + (mt * 16 + n15) * SX + kc * 32 + q * 8);
        acc2[mt] = __builtin_amdgcn_mfma_f32_16x16x32_bf16(A, B, acc2[mt], 0, 0, 0);
      }
    }

    // store (fire-and-forget; complementary wave halves now temporally close)
#pragma unroll
    for (int mt = 0; mt < 4; ++mt) {
      float* op = out + base + (mt * 16 + q * 4) * HW + nb + n15;
      f4_t a = acc2[mt];
#pragma unroll
      for (int r = 0; r < 4; ++r) op[r * HW] = a[r];
    }

    // re-sync waves: raw barrier, NO memory drain (no cross-wave sharing in
    // this loop; XH rows wave-private) -> prefetch loads stay in flight.
    __builtin_amdgcn_s_barrier();
  }
}

extern "C" void kernel_launch(void* const* d_in, const int* in_sizes, int n_in,
                              void* d_out, int out_size, void* d_ws, size_t ws_size,
                              hipStream_t stream) {
  const float* x     = (const float*)d_in[0];   // (4,64,256,256)
  const float* illu  = (const float*)d_in[1];   // (4,64,256,256)
  const float* wvs   = (const float*)d_in[4];   // w_v_spec (64,64)
  const float* wvt   = (const float*)d_in[7];   // w_v_spat (64,64)
  const float* wproj = (const float*)d_in[10];  // w_proj   (64,64)
  float* out = (float*)d_out;

  fused_hsattn<<<4 * (HW / PT) / TPB, 256, 0, stream>>>(x, illu, wvs, wvt,
                                                        wproj, out);
}